// Round 2
// baseline (543.441 us; speedup 1.0000x reference)
//
#include <hip/hip_runtime.h>
#include <hip/hip_cooperative_groups.h>

namespace cg = cooperative_groups;

#define N_NODES 100000
#define N_EDGES 1600000
#define IN_F 256
#define OUT_F 128

#define NBUCK 1563              // ceil(N_NODES / 64) dst-buckets of 64 nodes
#define NCH   250               // chunks over the edge list
#define CH    6400              // edges per chunk; NCH*CH == N_EDGES exactly
#define CBT   1024              // coop kernel block threads (16 waves/CU resident)
#define EPT   7                 // ceil(CH / CBT) edges per thread in coop phases
#define LIST_CAP 1024           // per half-bucket; mean 512, ~22 sigma headroom

typedef __attribute__((ext_vector_type(8))) short bf16x8;
typedef __attribute__((ext_vector_type(4))) float f32x4;

static __device__ __forceinline__ unsigned f2bf_u(float f) {
    unsigned u = __float_as_uint(f);
    return (u + 0x7FFFu + ((u >> 16) & 1u)) >> 16;      // RNE; inputs finite
}
static __device__ __forceinline__ float bf2f(short s) {
    return __uint_as_float(((unsigned)(unsigned short)s) << 16);
}

// ---------- cooperative partition pipeline ----------
// phase 0: per-chunk LDS histogram (edges stashed in registers)
// phase 1: per-bucket exclusive scan over chunks (blocks 0-1) || wprep (blocks 16-19)
// phase 2: exclusive scan of bucket totals (block 0)
// phase 3: scatter into exact CSR via LDS cursors (edges from registers)
__global__ __launch_bounds__(CBT) void part_coop_kernel(
    const int* __restrict__ edge_src, const int* __restrict__ edge_dst,
    const float* __restrict__ edge_weight, const float* __restrict__ w,
    int* __restrict__ hist, int* __restrict__ btot, int* __restrict__ bstart,
    int2* __restrict__ part, unsigned short* __restrict__ wtf) {
    cg::grid_group grid = cg::this_grid();
    __shared__ int h[NBUCK];
    __shared__ int wsum[CBT / 64];

    const int t = threadIdx.x;
    const int c = blockIdx.x;
    const int e0 = c * CH;

    // ---- phase 0: histogram; keep this thread's edges in registers ----
    for (int i = t; i < NBUCK; i += CBT) h[i] = 0;
    __syncthreads();
    int dv[EPT], sv[EPT], wv[EPT];
    #pragma unroll
    for (int i = 0; i < EPT; ++i) {
        const int k = i * CBT + t;
        dv[i] = -1;
        if (k < CH) {
            const int e = e0 + k;
            dv[i] = edge_dst[e];
            sv[i] = edge_src[e];
            wv[i] = __float_as_int(edge_weight[e]);
            atomicAdd(&h[dv[i] >> 6], 1);
        }
    }
    __syncthreads();
    {
        int* o = hist + (size_t)c * NBUCK;
        for (int i = t; i < NBUCK; i += CBT) o[i] = h[i];
    }
    __threadfence();
    grid.sync();

    // ---- phase 1: column scan over chunks || weight prep ----
    const int gt = c * CBT + t;
    if (gt < NBUCK) {
        int run = 0;
        #pragma unroll 10
        for (int ch = 0; ch < NCH; ++ch) {
            const size_t idx = (size_t)ch * NBUCK + gt;
            const int v = hist[idx];
            hist[idx] = run;                              // chunk-exclusive within bucket
            run += v;
        }
        btot[gt] = run;
    } else if (c >= 16 && c < 20) {
        // wtf[(ks*8+nt)*512 + lane*8 + j] = bf16(w[(ks*32+q*8+j)*128 + nt*16+m])
        const int id = (c - 16) * CBT + t;               // 0..4095 = 64 frags x 64 lanes
        const int f = id >> 6, lane = id & 63;
        const int ks = f >> 3, nt = f & 7;
        const int m = lane & 15, q = lane >> 4;
        const int row = nt * 16 + m;
        const int col0 = ks * 32 + q * 8;
        unsigned short* o = wtf + (size_t)f * 512 + lane * 8;
        #pragma unroll
        for (int jj = 0; jj < 8; ++jj)
            o[jj] = (unsigned short)f2bf_u(w[(size_t)(col0 + jj) * OUT_F + row]);
    }
    __threadfence();
    grid.sync();

    // ---- phase 2: exclusive scan of 1563 bucket totals (block 0) ----
    if (c == 0) {
        const int lane = t & 63, wave = t >> 6;
        int v[2];
        int s = 0;
        #pragma unroll
        for (int jj = 0; jj < 2; ++jj) {                 // 2*1024 = 2048 >= 1563
            const int i = t * 2 + jj;
            v[jj] = (i < NBUCK) ? btot[i] : 0;
            s += v[jj];
        }
        int sc = s;
        #pragma unroll
        for (int off = 1; off < 64; off <<= 1) {
            const int o = __shfl_up(sc, off);
            if (lane >= off) sc += o;
        }
        if (lane == 63) wsum[wave] = sc;
        __syncthreads();
        int add = 0;
        for (int w2 = 0; w2 < wave; ++w2) add += wsum[w2];
        int excl = add + sc - s;
        #pragma unroll
        for (int jj = 0; jj < 2; ++jj) {
            const int i = t * 2 + jj;
            if (i < NBUCK) bstart[i] = excl;
            excl += v[jj];
        }
        if (t == CBT - 1) bstart[NBUCK] = add + sc;      // sentinel = N_EDGES
        __threadfence();
    }
    grid.sync();

    // ---- phase 3: scatter from registers via LDS cursors ----
    {
        const int* hc = hist + (size_t)c * NBUCK;
        for (int i = t; i < NBUCK; i += CBT) h[i] = bstart[i] + hc[i];
    }
    __syncthreads();
    #pragma unroll
    for (int i = 0; i < EPT; ++i) {
        if (dv[i] >= 0) {
            const int pos = atomicAdd(&h[dv[i] >> 6], 1);
            part[pos] = make_int2(sv[i] | ((dv[i] & 63) << 24), wv[i]);
        }
    }
}

// ---------- MFMA GEMM, LDS-staged x, fragment-major wt ----------
// Block 256 = 4 waves; tile 64 rows. LDS: bf16 x-tile [64][264] = 33.8 KB.
__global__ __launch_bounds__(256) void gemm_mfma_kernel(const float* __restrict__ x,
                                                        const unsigned short* __restrict__ wtf,
                                                        unsigned short* __restrict__ hb) {
    __shared__ unsigned short xs[64][264];               // stride 264: 16B-aligned rows
    const int t = threadIdx.x;
    const int row0 = blockIdx.x * 64;

    // Stage: 64 rows x 256 fp32 -> bf16 LDS, coalesced (4096 float4 / 256 thr).
    const float4* x4 = (const float4*)x;
    #pragma unroll
    for (int i = 0; i < 16; ++i) {
        int idx = t + i * 256;
        int r = idx >> 6, c4 = idx & 63;
        int rg = row0 + r; if (rg >= N_NODES) rg = N_NODES - 1;
        float4 v = x4[(size_t)rg * 64 + c4];
        unsigned u0 = f2bf_u(v.x) | (f2bf_u(v.y) << 16);
        unsigned u1 = f2bf_u(v.z) | (f2bf_u(v.w) << 16);
        *(uint2*)&xs[r][c4 * 4] = make_uint2(u0, u1);
    }
    __syncthreads();

    const int wave = t >> 6, lane = t & 63;
    const int m = lane & 15, quad = lane >> 4;

    // All 8 A-frags up front (ds_read_b128 each).
    bf16x8 af[8];
    #pragma unroll
    for (int ks = 0; ks < 8; ++ks)
        af[ks] = *(const bf16x8*)&xs[wave * 16 + m][ks * 32 + quad * 8];

    f32x4 acc[8];
    #pragma unroll
    for (int nt = 0; nt < 8; ++nt) acc[nt] = (f32x4){0.f, 0.f, 0.f, 0.f};

    const bf16x8* wf = (const bf16x8*)wtf;               // frag-major, coalesced
    #pragma unroll
    for (int ks = 0; ks < 8; ++ks) {
        #pragma unroll
        for (int nt = 0; nt < 8; ++nt) {
            bf16x8 bf = wf[(size_t)(ks * 8 + nt) * 64 + lane];
            acc[nt] = __builtin_amdgcn_mfma_f32_16x16x32_bf16(af[ks], bf, acc[nt], 0, 0, 0);
        }
    }

    const int tile_base = row0 + wave * 16;
    #pragma unroll
    for (int nt = 0; nt < 8; ++nt) {
        #pragma unroll
        for (int r = 0; r < 4; ++r) {
            int orow = tile_base + quad * 4 + r;         // C/D: col=lane&15, row=quad*4+reg
            if (orow < N_NODES)
                hb[(size_t)orow * OUT_F + nt * 16 + m] = (unsigned short)f2bf_u(acc[nt][r]);
        }
    }
}

// ---------- fused SpMM: one block per 32-node half-bucket ----------
__global__ __launch_bounds__(256) void spmm_kernel(const unsigned short* __restrict__ hb,
                                                   const int* __restrict__ bstart,
                                                   const int2* __restrict__ part,
                                                   const float* __restrict__ b,
                                                   float* __restrict__ out) {
    __shared__ int lh[32];
    __shared__ int lstart[33];
    __shared__ int lcur[32];
    __shared__ int2 list[LIST_CAP];

    const int t = threadIdx.x;
    const int bucket = blockIdx.x >> 1;
    const int half = blockIdx.x & 1;
    const int base = bucket * 64 + half * 32;

    const int s0 = bstart[bucket];
    int cntb = bstart[bucket + 1] - s0;
    if (cntb > 2048) cntb = 2048;                        // statistically unreachable

    if (t < 32) lh[t] = 0;
    __syncthreads();

    // Pass 1: read bucket segment; stash only this half's edges.
    int2 stash[8];
    int  sn[8];
    #pragma unroll
    for (int sub = 0; sub < 8; ++sub) {
        const int idx = sub * 256 + t;
        sn[sub] = -1;
        if (idx < cntb) {
            const int2 en = part[(size_t)s0 + idx];
            const int n = ((unsigned)en.x) >> 24;        // 0..63 within bucket
            if ((n >> 5) == half) {
                sn[sub] = n & 31;
                stash[sub] = make_int2(en.x & 0xFFFFFF, en.y);
                atomicAdd(&lh[n & 31], 1);
            }
        }
    }
    __syncthreads();

    // Shuffle exclusive scan of the 32 node counters (lanes 0-31 of wave 0).
    if (t < 32) {
        const int v = lh[t];
        int s = v;
        #pragma unroll
        for (int off = 1; off < 32; off <<= 1) {
            const int o = __shfl_up(s, off);
            if (t >= off) s += o;
        }
        const int st = s - v;
        lstart[t] = st < LIST_CAP ? st : LIST_CAP;
        lcur[t]   = st;
        if (t == 31) lstart[32] = s < LIST_CAP ? s : LIST_CAP;
    }
    __syncthreads();

    // Pass 2: scatter stashed edges into per-node LDS lists.
    #pragma unroll
    for (int sub = 0; sub < 8; ++sub) {
        if (sn[sub] >= 0) {
            const int pos = atomicAdd(&lcur[sn[sub]], 1);
            if (pos < LIST_CAP) list[pos] = stash[sub];
        }
    }
    __syncthreads();

    // Gather: 16 lanes per node, 2 node-groups, 4-deep MLP unroll.
    const int j = t & 15;
    const float4* b4 = (const float4*)b;
    const float4 bb0 = b4[j * 2];
    const float4 bb1 = b4[j * 2 + 1];

    #pragma unroll
    for (int g = 0; g < 2; ++g) {
        const int n = g * 16 + (t >> 4);
        const int node = base + n;
        if (node >= N_NODES) continue;
        float4 acc0 = bb0, acc1 = bb1;
        int p = lstart[n];
        const int p1 = lstart[n + 1];
        for (; p + 4 <= p1; p += 4) {
            const int2 sw0 = list[p];
            const int2 sw1 = list[p + 1];
            const int2 sw2 = list[p + 2];
            const int2 sw3 = list[p + 3];
            const bf16x8 h0 = *(const bf16x8*)(hb + (size_t)sw0.x * OUT_F + j * 8);
            const bf16x8 h1 = *(const bf16x8*)(hb + (size_t)sw1.x * OUT_F + j * 8);
            const bf16x8 h2 = *(const bf16x8*)(hb + (size_t)sw2.x * OUT_F + j * 8);
            const bf16x8 h3 = *(const bf16x8*)(hb + (size_t)sw3.x * OUT_F + j * 8);
            const float w0 = __int_as_float(sw0.y);
            const float w1 = __int_as_float(sw1.y);
            const float w2 = __int_as_float(sw2.y);
            const float w3 = __int_as_float(sw3.y);
            acc0.x += w0 * bf2f(h0[0]); acc0.y += w0 * bf2f(h0[1]);
            acc0.z += w0 * bf2f(h0[2]); acc0.w += w0 * bf2f(h0[3]);
            acc1.x += w0 * bf2f(h0[4]); acc1.y += w0 * bf2f(h0[5]);
            acc1.z += w0 * bf2f(h0[6]); acc1.w += w0 * bf2f(h0[7]);
            acc0.x += w1 * bf2f(h1[0]); acc0.y += w1 * bf2f(h1[1]);
            acc0.z += w1 * bf2f(h1[2]); acc0.w += w1 * bf2f(h1[3]);
            acc1.x += w1 * bf2f(h1[4]); acc1.y += w1 * bf2f(h1[5]);
            acc1.z += w1 * bf2f(h1[6]); acc1.w += w1 * bf2f(h1[7]);
            acc0.x += w2 * bf2f(h2[0]); acc0.y += w2 * bf2f(h2[1]);
            acc0.z += w2 * bf2f(h2[2]); acc0.w += w2 * bf2f(h2[3]);
            acc1.x += w2 * bf2f(h2[4]); acc1.y += w2 * bf2f(h2[5]);
            acc1.z += w2 * bf2f(h2[6]); acc1.w += w2 * bf2f(h2[7]);
            acc0.x += w3 * bf2f(h3[0]); acc0.y += w3 * bf2f(h3[1]);
            acc0.z += w3 * bf2f(h3[2]); acc0.w += w3 * bf2f(h3[3]);
            acc1.x += w3 * bf2f(h3[4]); acc1.y += w3 * bf2f(h3[5]);
            acc1.z += w3 * bf2f(h3[6]); acc1.w += w3 * bf2f(h3[7]);
        }
        for (; p < p1; ++p) {
            const int2 sw = list[p];
            const float wgt = __int_as_float(sw.y);
            const bf16x8 hv = *(const bf16x8*)(hb + (size_t)sw.x * OUT_F + j * 8);
            acc0.x += wgt * bf2f(hv[0]); acc0.y += wgt * bf2f(hv[1]);
            acc0.z += wgt * bf2f(hv[2]); acc0.w += wgt * bf2f(hv[3]);
            acc1.x += wgt * bf2f(hv[4]); acc1.y += wgt * bf2f(hv[5]);
            acc1.z += wgt * bf2f(hv[6]); acc1.w += wgt * bf2f(hv[7]);
        }
        float4* o4 = (float4*)(out + (size_t)node * OUT_F + j * 8);
        o4[0] = acc0;
        o4[1] = acc1;
    }
}

extern "C" void kernel_launch(void* const* d_in, const int* in_sizes, int n_in,
                              void* d_out, int out_size, void* d_ws, size_t ws_size,
                              hipStream_t stream) {
    const float* x           = (const float*)d_in[0];
    const int*   edge_src    = (const int*)d_in[1];
    const int*   edge_dst    = (const int*)d_in[2];
    const float* edge_weight = (const float*)d_in[3];
    const float* w           = (const float*)d_in[4];
    const float* b           = (const float*)d_in[5];
    float* out = (float*)d_out;

    // workspace layout (16B-aligned), total ~40 MB
    char* ws = (char*)d_ws;
    size_t off = 0;
    unsigned short* hb  = (unsigned short*)(ws + off);
    off += (size_t)N_NODES * OUT_F * 2;           off = (off + 15) & ~(size_t)15;  // 25.6 MB
    unsigned short* wtf = (unsigned short*)(ws + off);
    off += (size_t)IN_F * OUT_F * 2;              off = (off + 15) & ~(size_t)15;  // 64 KB
    int* hist = (int*)(ws + off);
    off += (size_t)NCH * NBUCK * 4;               off = (off + 15) & ~(size_t)15;  // 1.56 MB
    int* btot = (int*)(ws + off);
    off += (size_t)NBUCK * 4;                     off = (off + 15) & ~(size_t)15;
    int* bstart = (int*)(ws + off);
    off += (size_t)(NBUCK + 1) * 4;               off = (off + 15) & ~(size_t)15;
    int2* part = (int2*)(ws + off);
    off += (size_t)N_EDGES * 8;                                                    // 12.8 MB

    void* cargs[9];
    cargs[0] = (void*)&edge_src;
    cargs[1] = (void*)&edge_dst;
    cargs[2] = (void*)&edge_weight;
    cargs[3] = (void*)&w;
    cargs[4] = (void*)&hist;
    cargs[5] = (void*)&btot;
    cargs[6] = (void*)&bstart;
    cargs[7] = (void*)&part;
    cargs[8] = (void*)&wtf;
    hipLaunchCooperativeKernel((const void*)part_coop_kernel, dim3(NCH), dim3(CBT),
                               cargs, 0, stream);

    gemm_mfma_kernel<<<(N_NODES + 63) / 64, 256, 0, stream>>>(x, wtf, hb);
    spmm_kernel<<<2 * NBUCK, 256, 0, stream>>>(hb, bstart, part, b, out);
}

// Round 3
// 294.183 us; speedup vs baseline: 1.8473x; 1.8473x over previous
//
#include <hip/hip_runtime.h>

#define N_NODES 100000
#define N_EDGES 1600000
#define IN_F 256
#define OUT_F 128

#define NBUCK 1563              // ceil(N_NODES / 64) dst-buckets of 64 nodes
#define NCH   250               // chunks over the edge list
#define CH    6400              // edges per chunk; NCH*CH == N_EDGES exactly
#define LIST_CAP 1024           // per half-bucket; mean 512, ~22 sigma headroom

typedef __attribute__((ext_vector_type(8))) short bf16x8;
typedef __attribute__((ext_vector_type(4))) float f32x4;

static __device__ __forceinline__ unsigned f2bf_u(float f) {
    unsigned u = __float_as_uint(f);
    return (u + 0x7FFFu + ((u >> 16) & 1u)) >> 16;      // RNE; inputs finite
}
static __device__ __forceinline__ float bf2f(short s) {
    return __uint_as_float(((unsigned)(unsigned short)s) << 16);
}

// ---------- pass A: per-chunk bucket histogram (LDS atomics, 16 waves/CU) ----------
__global__ __launch_bounds__(1024) void hist_kernel(const int* __restrict__ edge_dst,
                                                    int* __restrict__ hist) {
    __shared__ int h[NBUCK];
    const int t = threadIdx.x;
    for (int i = t; i < NBUCK; i += 1024) h[i] = 0;
    __syncthreads();
    const int4* d4 = (const int4*)(edge_dst + blockIdx.x * CH);   // 16B-aligned: CH*4 % 16 == 0
    for (int k = t; k < CH / 4; k += 1024) {
        const int4 dd = d4[k];
        atomicAdd(&h[dd.x >> 6], 1);
        atomicAdd(&h[dd.y >> 6], 1);
        atomicAdd(&h[dd.z >> 6], 1);
        atomicAdd(&h[dd.w >> 6], 1);
    }
    __syncthreads();
    int* o = hist + (size_t)blockIdx.x * NBUCK;                   // chunk-major: contiguous
    for (int i = t; i < NBUCK; i += 1024) o[i] = h[i];
}

// ---------- pass B1: per-bucket exclusive scan over chunks (in place) ----------
// thread b walks its column; wave touches 64 consecutive ints per step.
// unroll 25 -> 10 sequential load-batches instead of 25 (latency chain).
__global__ __launch_bounds__(256) void scan1_kernel(int* __restrict__ hist,
                                                    int* __restrict__ btot) {
    const int b = blockIdx.x * 256 + threadIdx.x;
    if (b >= NBUCK) return;
    int run = 0;
    #pragma unroll 25
    for (int c = 0; c < NCH; ++c) {
        const size_t idx = (size_t)c * NBUCK + b;
        const int v = hist[idx];
        hist[idx] = run;                                  // chunk-exclusive within bucket
        run += v;
    }
    btot[b] = run;
}

// ---------- pass B2: block 0 scans bucket totals; blocks 1-16 do weight prep ----------
__global__ __launch_bounds__(256) void scan2_wprep_kernel(const int* __restrict__ btot,
                                                          int* __restrict__ bstart,
                                                          const float* __restrict__ w,
                                                          unsigned short* __restrict__ wtf) {
    const int t = threadIdx.x;
    if (blockIdx.x > 0) {
        // wtf[(ks*8+nt)*512 + lane*8 + j] = bf16(w[(ks*32+q*8+j)*128 + nt*16+m])
        const int id = (blockIdx.x - 1) * 256 + t;       // 0..4095 = 64 frags x 64 lanes
        const int f = id >> 6, lane = id & 63;
        const int ks = f >> 3, nt = f & 7;
        const int m = lane & 15, q = lane >> 4;
        const int row = nt * 16 + m;
        const int col0 = ks * 32 + q * 8;
        unsigned short* o = wtf + (size_t)f * 512 + lane * 8;
        #pragma unroll
        for (int j = 0; j < 8; ++j)
            o[j] = (unsigned short)f2bf_u(w[(size_t)(col0 + j) * OUT_F + row]);
        return;
    }
    __shared__ int wsum[4];
    const int lane = t & 63, wave = t >> 6;
    int v[7];
    int s = 0;
    #pragma unroll
    for (int j = 0; j < 7; ++j) {                         // 7*256 = 1792 >= 1563
        const int i = t * 7 + j;
        v[j] = (i < NBUCK) ? btot[i] : 0;
        s += v[j];
    }
    int sc = s;
    #pragma unroll
    for (int off = 1; off < 64; off <<= 1) {
        const int o = __shfl_up(sc, off);
        if (lane >= off) sc += o;
    }
    if (lane == 63) wsum[wave] = sc;
    __syncthreads();
    int add = 0;
    for (int w2 = 0; w2 < wave; ++w2) add += wsum[w2];
    int excl = add + sc - s;
    #pragma unroll
    for (int j = 0; j < 7; ++j) {
        const int i = t * 7 + j;
        if (i < NBUCK) bstart[i] = excl;
        excl += v[j];
    }
    if (t == 255) bstart[NBUCK] = add + sc;               // sentinel = N_EDGES
}

// ---------- pass C: scatter into exact CSR via LDS cursors (16 waves/CU) ----------
__global__ __launch_bounds__(1024) void scatter_kernel(const int* __restrict__ edge_src,
                                                       const int* __restrict__ edge_dst,
                                                       const float* __restrict__ edge_weight,
                                                       const int* __restrict__ hist,
                                                       const int* __restrict__ bstart,
                                                       int2* __restrict__ part) {
    __shared__ int cur[NBUCK];
    const int t = threadIdx.x;
    const int c = blockIdx.x;
    const int* hc = hist + (size_t)c * NBUCK;
    for (int i = t; i < NBUCK; i += 1024) cur[i] = bstart[i] + hc[i];
    __syncthreads();
    const int e0 = c * CH;
    const int4*   d4 = (const int4*)(edge_dst + e0);
    const int4*   s4 = (const int4*)(edge_src + e0);
    const float4* w4 = (const float4*)(edge_weight + e0);
    for (int k = t; k < CH / 4; k += 1024) {
        const int4   dd = d4[k];
        const int4   ss = s4[k];
        const float4 ww = w4[k];
        int pos;
        pos = atomicAdd(&cur[dd.x >> 6], 1);
        part[pos] = make_int2(ss.x | ((dd.x & 63) << 24), __float_as_int(ww.x));
        pos = atomicAdd(&cur[dd.y >> 6], 1);
        part[pos] = make_int2(ss.y | ((dd.y & 63) << 24), __float_as_int(ww.y));
        pos = atomicAdd(&cur[dd.z >> 6], 1);
        part[pos] = make_int2(ss.z | ((dd.z & 63) << 24), __float_as_int(ww.z));
        pos = atomicAdd(&cur[dd.w >> 6], 1);
        part[pos] = make_int2(ss.w | ((dd.w & 63) << 24), __float_as_int(ww.w));
    }
}

// ---------- MFMA GEMM, LDS-staged x, fragment-major wt ----------
// Block 256 = 4 waves; tile 64 rows. LDS: bf16 x-tile [64][264] = 33.8 KB.
__global__ __launch_bounds__(256) void gemm_mfma_kernel(const float* __restrict__ x,
                                                        const unsigned short* __restrict__ wtf,
                                                        unsigned short* __restrict__ hb) {
    __shared__ unsigned short xs[64][264];               // stride 264: 16B-aligned rows
    const int t = threadIdx.x;
    const int row0 = blockIdx.x * 64;

    // Stage: 64 rows x 256 fp32 -> bf16 LDS, coalesced (4096 float4 / 256 thr).
    const float4* x4 = (const float4*)x;
    #pragma unroll
    for (int i = 0; i < 16; ++i) {
        int idx = t + i * 256;
        int r = idx >> 6, c4 = idx & 63;
        int rg = row0 + r; if (rg >= N_NODES) rg = N_NODES - 1;
        float4 v = x4[(size_t)rg * 64 + c4];
        unsigned u0 = f2bf_u(v.x) | (f2bf_u(v.y) << 16);
        unsigned u1 = f2bf_u(v.z) | (f2bf_u(v.w) << 16);
        *(uint2*)&xs[r][c4 * 4] = make_uint2(u0, u1);
    }
    __syncthreads();

    const int wave = t >> 6, lane = t & 63;
    const int m = lane & 15, quad = lane >> 4;

    // All 8 A-frags up front (ds_read_b128 each).
    bf16x8 af[8];
    #pragma unroll
    for (int ks = 0; ks < 8; ++ks)
        af[ks] = *(const bf16x8*)&xs[wave * 16 + m][ks * 32 + quad * 8];

    f32x4 acc[8];
    #pragma unroll
    for (int nt = 0; nt < 8; ++nt) acc[nt] = (f32x4){0.f, 0.f, 0.f, 0.f};

    const bf16x8* wf = (const bf16x8*)wtf;               // frag-major, coalesced
    #pragma unroll
    for (int ks = 0; ks < 8; ++ks) {
        #pragma unroll
        for (int nt = 0; nt < 8; ++nt) {
            bf16x8 bf = wf[(size_t)(ks * 8 + nt) * 64 + lane];
            acc[nt] = __builtin_amdgcn_mfma_f32_16x16x32_bf16(af[ks], bf, acc[nt], 0, 0, 0);
        }
    }

    const int tile_base = row0 + wave * 16;
    #pragma unroll
    for (int nt = 0; nt < 8; ++nt) {
        #pragma unroll
        for (int r = 0; r < 4; ++r) {
            int orow = tile_base + quad * 4 + r;         // C/D: col=lane&15, row=quad*4+reg
            if (orow < N_NODES)
                hb[(size_t)orow * OUT_F + nt * 16 + m] = (unsigned short)f2bf_u(acc[nt][r]);
        }
    }
}

// ---------- fused SpMM: one block per 32-node half-bucket ----------
__global__ __launch_bounds__(256) void spmm_kernel(const unsigned short* __restrict__ hb,
                                                   const int* __restrict__ bstart,
                                                   const int2* __restrict__ part,
                                                   const float* __restrict__ b,
                                                   float* __restrict__ out) {
    __shared__ int lh[32];
    __shared__ int lstart[33];
    __shared__ int lcur[32];
    __shared__ int2 list[LIST_CAP];

    const int t = threadIdx.x;
    const int bucket = blockIdx.x >> 1;
    const int half = blockIdx.x & 1;
    const int base = bucket * 64 + half * 32;

    const int s0 = bstart[bucket];
    int cntb = bstart[bucket + 1] - s0;
    if (cntb > 2048) cntb = 2048;                        // statistically unreachable

    if (t < 32) lh[t] = 0;
    __syncthreads();

    // Pass 1: read bucket segment; stash only this half's edges.
    int2 stash[8];
    int  sn[8];
    #pragma unroll
    for (int sub = 0; sub < 8; ++sub) {
        const int idx = sub * 256 + t;
        sn[sub] = -1;
        if (idx < cntb) {
            const int2 en = part[(size_t)s0 + idx];
            const int n = ((unsigned)en.x) >> 24;        // 0..63 within bucket
            if ((n >> 5) == half) {
                sn[sub] = n & 31;
                stash[sub] = make_int2(en.x & 0xFFFFFF, en.y);
                atomicAdd(&lh[n & 31], 1);
            }
        }
    }
    __syncthreads();

    // Shuffle exclusive scan of the 32 node counters (lanes 0-31 of wave 0).
    if (t < 32) {
        const int v = lh[t];
        int s = v;
        #pragma unroll
        for (int off = 1; off < 32; off <<= 1) {
            const int o = __shfl_up(s, off);
            if (t >= off) s += o;
        }
        const int st = s - v;
        lstart[t] = st < LIST_CAP ? st : LIST_CAP;
        lcur[t]   = st;
        if (t == 31) lstart[32] = s < LIST_CAP ? s : LIST_CAP;
    }
    __syncthreads();

    // Pass 2: scatter stashed edges into per-node LDS lists.
    #pragma unroll
    for (int sub = 0; sub < 8; ++sub) {
        if (sn[sub] >= 0) {
            const int pos = atomicAdd(&lcur[sn[sub]], 1);
            if (pos < LIST_CAP) list[pos] = stash[sub];
        }
    }
    __syncthreads();

    // Gather: 16 lanes per node, 2 node-groups, 4-deep MLP unroll.
    const int j = t & 15;
    const float4* b4 = (const float4*)b;
    const float4 bb0 = b4[j * 2];
    const float4 bb1 = b4[j * 2 + 1];

    #pragma unroll
    for (int g = 0; g < 2; ++g) {
        const int n = g * 16 + (t >> 4);
        const int node = base + n;
        if (node >= N_NODES) continue;
        float4 acc0 = bb0, acc1 = bb1;
        int p = lstart[n];
        const int p1 = lstart[n + 1];
        for (; p + 4 <= p1; p += 4) {
            const int2 sw0 = list[p];
            const int2 sw1 = list[p + 1];
            const int2 sw2 = list[p + 2];
            const int2 sw3 = list[p + 3];
            const bf16x8 h0 = *(const bf16x8*)(hb + (size_t)sw0.x * OUT_F + j * 8);
            const bf16x8 h1 = *(const bf16x8*)(hb + (size_t)sw1.x * OUT_F + j * 8);
            const bf16x8 h2 = *(const bf16x8*)(hb + (size_t)sw2.x * OUT_F + j * 8);
            const bf16x8 h3 = *(const bf16x8*)(hb + (size_t)sw3.x * OUT_F + j * 8);
            const float w0 = __int_as_float(sw0.y);
            const float w1 = __int_as_float(sw1.y);
            const float w2 = __int_as_float(sw2.y);
            const float w3 = __int_as_float(sw3.y);
            acc0.x += w0 * bf2f(h0[0]); acc0.y += w0 * bf2f(h0[1]);
            acc0.z += w0 * bf2f(h0[2]); acc0.w += w0 * bf2f(h0[3]);
            acc1.x += w0 * bf2f(h0[4]); acc1.y += w0 * bf2f(h0[5]);
            acc1.z += w0 * bf2f(h0[6]); acc1.w += w0 * bf2f(h0[7]);
            acc0.x += w1 * bf2f(h1[0]); acc0.y += w1 * bf2f(h1[1]);
            acc0.z += w1 * bf2f(h1[2]); acc0.w += w1 * bf2f(h1[3]);
            acc1.x += w1 * bf2f(h1[4]); acc1.y += w1 * bf2f(h1[5]);
            acc1.z += w1 * bf2f(h1[6]); acc1.w += w1 * bf2f(h1[7]);
            acc0.x += w2 * bf2f(h2[0]); acc0.y += w2 * bf2f(h2[1]);
            acc0.z += w2 * bf2f(h2[2]); acc0.w += w2 * bf2f(h2[3]);
            acc1.x += w2 * bf2f(h2[4]); acc1.y += w2 * bf2f(h2[5]);
            acc1.z += w2 * bf2f(h2[6]); acc1.w += w2 * bf2f(h2[7]);
            acc0.x += w3 * bf2f(h3[0]); acc0.y += w3 * bf2f(h3[1]);
            acc0.z += w3 * bf2f(h3[2]); acc0.w += w3 * bf2f(h3[3]);
            acc1.x += w3 * bf2f(h3[4]); acc1.y += w3 * bf2f(h3[5]);
            acc1.z += w3 * bf2f(h3[6]); acc1.w += w3 * bf2f(h3[7]);
        }
        for (; p < p1; ++p) {
            const int2 sw = list[p];
            const float wgt = __int_as_float(sw.y);
            const bf16x8 hv = *(const bf16x8*)(hb + (size_t)sw.x * OUT_F + j * 8);
            acc0.x += wgt * bf2f(hv[0]); acc0.y += wgt * bf2f(hv[1]);
            acc0.z += wgt * bf2f(hv[2]); acc0.w += wgt * bf2f(hv[3]);
            acc1.x += wgt * bf2f(hv[4]); acc1.y += wgt * bf2f(hv[5]);
            acc1.z += wgt * bf2f(hv[6]); acc1.w += wgt * bf2f(hv[7]);
        }
        float4* o4 = (float4*)(out + (size_t)node * OUT_F + j * 8);
        o4[0] = acc0;
        o4[1] = acc1;
    }
}

extern "C" void kernel_launch(void* const* d_in, const int* in_sizes, int n_in,
                              void* d_out, int out_size, void* d_ws, size_t ws_size,
                              hipStream_t stream) {
    const float* x           = (const float*)d_in[0];
    const int*   edge_src    = (const int*)d_in[1];
    const int*   edge_dst    = (const int*)d_in[2];
    const float* edge_weight = (const float*)d_in[3];
    const float* w           = (const float*)d_in[4];
    const float* b           = (const float*)d_in[5];
    float* out = (float*)d_out;

    // workspace layout (16B-aligned), total ~40 MB
    char* ws = (char*)d_ws;
    size_t off = 0;
    unsigned short* hb  = (unsigned short*)(ws + off);
    off += (size_t)N_NODES * OUT_F * 2;           off = (off + 15) & ~(size_t)15;  // 25.6 MB
    unsigned short* wtf = (unsigned short*)(ws + off);
    off += (size_t)IN_F * OUT_F * 2;              off = (off + 15) & ~(size_t)15;  // 64 KB
    int* hist = (int*)(ws + off);
    off += (size_t)NCH * NBUCK * 4;               off = (off + 15) & ~(size_t)15;  // 1.56 MB
    int* btot = (int*)(ws + off);
    off += (size_t)NBUCK * 4;                     off = (off + 15) & ~(size_t)15;
    int* bstart = (int*)(ws + off);
    off += (size_t)(NBUCK + 1) * 4;               off = (off + 15) & ~(size_t)15;
    int2* part = (int2*)(ws + off);
    off += (size_t)N_EDGES * 8;                                                    // 12.8 MB

    hist_kernel <<<NCH, 1024, 0, stream>>>(edge_dst, hist);
    scan1_kernel<<<(NBUCK + 255) / 256, 256, 0, stream>>>(hist, btot);
    scan2_wprep_kernel<<<17, 256, 0, stream>>>(btot, bstart, w, wtf);
    scatter_kernel<<<NCH, 1024, 0, stream>>>(edge_src, edge_dst, edge_weight, hist, bstart, part);
    gemm_mfma_kernel<<<(N_NODES + 63) / 64, 256, 0, stream>>>(x, wtf, hb);
    spmm_kernel<<<2 * NBUCK, 256, 0, stream>>>(hb, bstart, part, b, out);
}

// Round 4
// 289.116 us; speedup vs baseline: 1.8797x; 1.0175x over previous
//
#include <hip/hip_runtime.h>

#define N_NODES 100000
#define N_EDGES 1600000
#define IN_F 256
#define OUT_F 128

#define NBUCK 1563              // ceil(N_NODES / 64) dst-buckets of 64 nodes
#define NCH   250               // chunks over the edge list
#define CH    6400              // edges per chunk; NCH*CH == N_EDGES exactly
#define BCAP  2048              // per-bucket capacity; mean 1024, sd 32 -> 32 sigma

typedef __attribute__((ext_vector_type(8))) short bf16x8;
typedef __attribute__((ext_vector_type(4))) float f32x4;

static __device__ __forceinline__ unsigned f2bf_u(float f) {
    unsigned u = __float_as_uint(f);
    return (u + 0x7FFFu + ((u >> 16) & 1u)) >> 16;      // RNE; inputs finite
}
static __device__ __forceinline__ float bf2f(short s) {
    return __uint_as_float(((unsigned)(unsigned short)s) << 16);
}

// ---------- init: block 0 zeros bucket cursors; blocks 1-4 do weight prep ----------
__global__ __launch_bounds__(1024) void init_kernel(int* __restrict__ gadd,
                                                    const float* __restrict__ w,
                                                    unsigned short* __restrict__ wtf) {
    const int t = threadIdx.x;
    if (blockIdx.x == 0) {
        for (int i = t; i < NBUCK; i += 1024) gadd[i] = 0;
        return;
    }
    // wtf[(ks*8+nt)*512 + lane*8 + j] = bf16(w[(ks*32+q*8+j)*128 + nt*16+m])
    const int id = (blockIdx.x - 1) * 1024 + t;          // 0..4095 = 64 frags x 64 lanes
    const int f = id >> 6, lane = id & 63;
    const int ks = f >> 3, nt = f & 7;
    const int m = lane & 15, q = lane >> 4;
    const int row = nt * 16 + m;
    const int col0 = ks * 32 + q * 8;
    unsigned short* o = wtf + (size_t)f * 512 + lane * 8;
    #pragma unroll
    for (int j = 0; j < 8; ++j)
        o[j] = (unsigned short)f2bf_u(w[(size_t)(col0 + j) * OUT_F + row]);
}

// ---------- single-kernel partition: LDS hist -> bulk global reserve -> scatter ----------
// Each (block,bucket) writes ONE contiguous run (~8 edges = 64B), so part lines are
// filled within a block's lifetime: no write amplification. No scans needed because
// spmm consumes bucket segments unordered.
__global__ __launch_bounds__(1024) void part_kernel(const int* __restrict__ edge_src,
                                                    const int* __restrict__ edge_dst,
                                                    const float* __restrict__ edge_weight,
                                                    int* __restrict__ gadd,
                                                    int2* __restrict__ part) {
    __shared__ int h[NBUCK];
    const int t = threadIdx.x;
    const int c = blockIdx.x;
    for (int i = t; i < NBUCK; i += 1024) h[i] = 0;
    __syncthreads();

    const int e0 = c * CH;
    const int4*   d4 = (const int4*)(edge_dst + e0);     // 16B-aligned: CH*4 % 16 == 0
    const int4*   s4 = (const int4*)(edge_src + e0);
    const float4* w4 = (const float4*)(edge_weight + e0);

    // pass 1: LDS histogram of this chunk
    for (int k = t; k < CH / 4; k += 1024) {
        const int4 dd = d4[k];
        atomicAdd(&h[dd.x >> 6], 1);
        atomicAdd(&h[dd.y >> 6], 1);
        atomicAdd(&h[dd.z >> 6], 1);
        atomicAdd(&h[dd.w >> 6], 1);
    }
    __syncthreads();

    // reserve: one global atomic per non-empty bucket; h[b] becomes absolute cursor
    for (int i = t; i < NBUCK; i += 1024) {
        const int cnt = h[i];
        int base = 0;
        if (cnt > 0) base = atomicAdd(&gadd[i], cnt);
        h[i] = i * BCAP + base;
    }
    __syncthreads();

    // pass 2: scatter through LDS cursors (dst/src/w re-read, L2-hot)
    for (int k = t; k < CH / 4; k += 1024) {
        const int4   dd = d4[k];
        const int4   ss = s4[k];
        const float4 ww = w4[k];
        int b, pos;
        b = dd.x >> 6; pos = atomicAdd(&h[b], 1);
        if (pos < (b + 1) * BCAP)
            part[pos] = make_int2(ss.x | ((dd.x & 63) << 24), __float_as_int(ww.x));
        b = dd.y >> 6; pos = atomicAdd(&h[b], 1);
        if (pos < (b + 1) * BCAP)
            part[pos] = make_int2(ss.y | ((dd.y & 63) << 24), __float_as_int(ww.y));
        b = dd.z >> 6; pos = atomicAdd(&h[b], 1);
        if (pos < (b + 1) * BCAP)
            part[pos] = make_int2(ss.z | ((dd.z & 63) << 24), __float_as_int(ww.z));
        b = dd.w >> 6; pos = atomicAdd(&h[b], 1);
        if (pos < (b + 1) * BCAP)
            part[pos] = make_int2(ss.w | ((dd.w & 63) << 24), __float_as_int(ww.w));
    }
}

// ---------- MFMA GEMM, LDS-staged x, fragment-major wt ----------
// Block 256 = 4 waves; tile 64 rows. LDS: bf16 x-tile [64][264] = 33.8 KB.
__global__ __launch_bounds__(256) void gemm_mfma_kernel(const float* __restrict__ x,
                                                        const unsigned short* __restrict__ wtf,
                                                        unsigned short* __restrict__ hb) {
    __shared__ unsigned short xs[64][264];               // stride 264: 16B-aligned rows
    const int t = threadIdx.x;
    const int row0 = blockIdx.x * 64;

    // Stage: 64 rows x 256 fp32 -> bf16 LDS, coalesced (4096 float4 / 256 thr).
    const float4* x4 = (const float4*)x;
    #pragma unroll
    for (int i = 0; i < 16; ++i) {
        int idx = t + i * 256;
        int r = idx >> 6, c4 = idx & 63;
        int rg = row0 + r; if (rg >= N_NODES) rg = N_NODES - 1;
        float4 v = x4[(size_t)rg * 64 + c4];
        unsigned u0 = f2bf_u(v.x) | (f2bf_u(v.y) << 16);
        unsigned u1 = f2bf_u(v.z) | (f2bf_u(v.w) << 16);
        *(uint2*)&xs[r][c4 * 4] = make_uint2(u0, u1);
    }
    __syncthreads();

    const int wave = t >> 6, lane = t & 63;
    const int m = lane & 15, quad = lane >> 4;

    // All 8 A-frags up front (ds_read_b128 each).
    bf16x8 af[8];
    #pragma unroll
    for (int ks = 0; ks < 8; ++ks)
        af[ks] = *(const bf16x8*)&xs[wave * 16 + m][ks * 32 + quad * 8];

    f32x4 acc[8];
    #pragma unroll
    for (int nt = 0; nt < 8; ++nt) acc[nt] = (f32x4){0.f, 0.f, 0.f, 0.f};

    const bf16x8* wf = (const bf16x8*)wtf;               // frag-major, coalesced
    #pragma unroll
    for (int ks = 0; ks < 8; ++ks) {
        #pragma unroll
        for (int nt = 0; nt < 8; ++nt) {
            bf16x8 bf = wf[(size_t)(ks * 8 + nt) * 64 + lane];
            acc[nt] = __builtin_amdgcn_mfma_f32_16x16x32_bf16(af[ks], bf, acc[nt], 0, 0, 0);
        }
    }

    const int tile_base = row0 + wave * 16;
    #pragma unroll
    for (int nt = 0; nt < 8; ++nt) {
        #pragma unroll
        for (int r = 0; r < 4; ++r) {
            int orow = tile_base + quad * 4 + r;         // C/D: col=lane&15, row=quad*4+reg
            if (orow < N_NODES)
                hb[(size_t)orow * OUT_F + nt * 16 + m] = (unsigned short)f2bf_u(acc[nt][r]);
        }
    }
}

// ---------- fused SpMM: one 512-thread block per 64-node bucket ----------
__global__ __launch_bounds__(512) void spmm_kernel(const unsigned short* __restrict__ hb,
                                                   const int* __restrict__ gadd,
                                                   const int2* __restrict__ part,
                                                   const float* __restrict__ b,
                                                   float* __restrict__ out) {
    __shared__ int lh[64];
    __shared__ int lstart[65];
    __shared__ int lcur[64];
    __shared__ int2 list[BCAP];

    const int t = threadIdx.x;
    const int bucket = blockIdx.x;
    const int base = bucket * 64;

    int cntb = gadd[bucket];
    if (cntb > BCAP) cntb = BCAP;                        // statistically unreachable
    const size_t s0 = (size_t)bucket * BCAP;

    if (t < 64) lh[t] = 0;
    __syncthreads();

    // Pass 1: read bucket segment into registers; LDS histogram over 64 nodes.
    int2 stash[4];
    int  sn[4];
    #pragma unroll
    for (int sub = 0; sub < 4; ++sub) {
        const int idx = sub * 512 + t;
        sn[sub] = -1;
        if (idx < cntb) {
            const int2 en = part[s0 + idx];
            const int n = ((unsigned)en.x) >> 24;        // 0..63 within bucket
            sn[sub] = n;
            stash[sub] = make_int2(en.x & 0xFFFFFF, en.y);
            atomicAdd(&lh[n], 1);
        }
    }
    __syncthreads();

    // Wave-0 shuffle exclusive scan of the 64 node counters.
    if (t < 64) {
        const int v = lh[t];
        int s = v;
        #pragma unroll
        for (int off = 1; off < 64; off <<= 1) {
            const int o = __shfl_up(s, off);
            if (t >= off) s += o;
        }
        lstart[t] = s - v;
        lcur[t]   = s - v;
        if (t == 63) lstart[64] = s;
    }
    __syncthreads();

    // Pass 2: scatter stashed edges into per-node LDS lists.
    #pragma unroll
    for (int sub = 0; sub < 4; ++sub) {
        if (sn[sub] >= 0) {
            const int pos = atomicAdd(&lcur[sn[sub]], 1);
            list[pos] = stash[sub];
        }
    }
    __syncthreads();

    // Gather: 16 lanes per node, 2 node-groups of 32, 4-deep MLP unroll.
    const int j = t & 15;
    const float4* b4 = (const float4*)b;
    const float4 bb0 = b4[j * 2];
    const float4 bb1 = b4[j * 2 + 1];

    #pragma unroll
    for (int g = 0; g < 2; ++g) {
        const int n = g * 32 + (t >> 4);
        const int node = base + n;
        if (node >= N_NODES) continue;
        float4 acc0 = bb0, acc1 = bb1;
        int p = lstart[n];
        const int p1 = lstart[n + 1];
        for (; p + 4 <= p1; p += 4) {
            const int2 sw0 = list[p];
            const int2 sw1 = list[p + 1];
            const int2 sw2 = list[p + 2];
            const int2 sw3 = list[p + 3];
            const bf16x8 h0 = *(const bf16x8*)(hb + (size_t)sw0.x * OUT_F + j * 8);
            const bf16x8 h1 = *(const bf16x8*)(hb + (size_t)sw1.x * OUT_F + j * 8);
            const bf16x8 h2 = *(const bf16x8*)(hb + (size_t)sw2.x * OUT_F + j * 8);
            const bf16x8 h3 = *(const bf16x8*)(hb + (size_t)sw3.x * OUT_F + j * 8);
            const float w0 = __int_as_float(sw0.y);
            const float w1 = __int_as_float(sw1.y);
            const float w2 = __int_as_float(sw2.y);
            const float w3 = __int_as_float(sw3.y);
            acc0.x += w0 * bf2f(h0[0]); acc0.y += w0 * bf2f(h0[1]);
            acc0.z += w0 * bf2f(h0[2]); acc0.w += w0 * bf2f(h0[3]);
            acc1.x += w0 * bf2f(h0[4]); acc1.y += w0 * bf2f(h0[5]);
            acc1.z += w0 * bf2f(h0[6]); acc1.w += w0 * bf2f(h0[7]);
            acc0.x += w1 * bf2f(h1[0]); acc0.y += w1 * bf2f(h1[1]);
            acc0.z += w1 * bf2f(h1[2]); acc0.w += w1 * bf2f(h1[3]);
            acc1.x += w1 * bf2f(h1[4]); acc1.y += w1 * bf2f(h1[5]);
            acc1.z += w1 * bf2f(h1[6]); acc1.w += w1 * bf2f(h1[7]);
            acc0.x += w2 * bf2f(h2[0]); acc0.y += w2 * bf2f(h2[1]);
            acc0.z += w2 * bf2f(h2[2]); acc0.w += w2 * bf2f(h2[3]);
            acc1.x += w2 * bf2f(h2[4]); acc1.y += w2 * bf2f(h2[5]);
            acc1.z += w2 * bf2f(h2[6]); acc1.w += w2 * bf2f(h2[7]);
            acc0.x += w3 * bf2f(h3[0]); acc0.y += w3 * bf2f(h3[1]);
            acc0.z += w3 * bf2f(h3[2]); acc0.w += w3 * bf2f(h3[3]);
            acc1.x += w3 * bf2f(h3[4]); acc1.y += w3 * bf2f(h3[5]);
            acc1.z += w3 * bf2f(h3[6]); acc1.w += w3 * bf2f(h3[7]);
        }
        for (; p < p1; ++p) {
            const int2 sw = list[p];
            const float wgt = __int_as_float(sw.y);
            const bf16x8 hv = *(const bf16x8*)(hb + (size_t)sw.x * OUT_F + j * 8);
            acc0.x += wgt * bf2f(hv[0]); acc0.y += wgt * bf2f(hv[1]);
            acc0.z += wgt * bf2f(hv[2]); acc0.w += wgt * bf2f(hv[3]);
            acc1.x += wgt * bf2f(hv[4]); acc1.y += wgt * bf2f(hv[5]);
            acc1.z += wgt * bf2f(hv[6]); acc1.w += wgt * bf2f(hv[7]);
        }
        float4* o4 = (float4*)(out + (size_t)node * OUT_F + j * 8);
        o4[0] = acc0;
        o4[1] = acc1;
    }
}

extern "C" void kernel_launch(void* const* d_in, const int* in_sizes, int n_in,
                              void* d_out, int out_size, void* d_ws, size_t ws_size,
                              hipStream_t stream) {
    const float* x           = (const float*)d_in[0];
    const int*   edge_src    = (const int*)d_in[1];
    const int*   edge_dst    = (const int*)d_in[2];
    const float* edge_weight = (const float*)d_in[3];
    const float* w           = (const float*)d_in[4];
    const float* b           = (const float*)d_in[5];
    float* out = (float*)d_out;

    // workspace layout (16B-aligned), total ~51.3 MB
    char* ws = (char*)d_ws;
    size_t off = 0;
    unsigned short* hb  = (unsigned short*)(ws + off);
    off += (size_t)N_NODES * OUT_F * 2;           off = (off + 15) & ~(size_t)15;  // 25.6 MB
    unsigned short* wtf = (unsigned short*)(ws + off);
    off += (size_t)IN_F * OUT_F * 2;              off = (off + 15) & ~(size_t)15;  // 64 KB
    int* gadd = (int*)(ws + off);
    off += (size_t)NBUCK * 4;                     off = (off + 15) & ~(size_t)15;  // 6 KB
    int2* part = (int2*)(ws + off);
    off += (size_t)NBUCK * BCAP * 8;                                               // 25.6 MB

    init_kernel<<<5, 1024, 0, stream>>>(gadd, w, wtf);
    part_kernel<<<NCH, 1024, 0, stream>>>(edge_src, edge_dst, edge_weight, gadd, part);
    gemm_mfma_kernel<<<(N_NODES + 63) / 64, 256, 0, stream>>>(x, wtf, hb);
    spmm_kernel<<<NBUCK, 512, 0, stream>>>(hb, gadd, part, b, out);
}